// Round 1
// baseline (762.233 us; speedup 1.0000x reference)
//
#include <hip/hip_runtime.h>
#include <hip/hip_bf16.h>
#include <stdint.h>

// Problem constants
#define B_   32
#define T_   2048
#define W_   1024
#define G_   16
#define D_   64
#define LIST_CAP 65536

typedef __bf16 bf16_t;
typedef __bf16 bf16x8 __attribute__((ext_vector_type(8)));
typedef float  f32x4  __attribute__((ext_vector_type(4)));

// ---------------- workspace layout (bytes) ----------------
// xT bf16 [32][1024][2048]  (k=t contiguous -> gemm_bt shape for Gram)
#define WS_XT      0ull
#define WS_XT_SZ   (134217728ull)                 // 32*1024*2048*2
#define WS_SUM     (WS_XT + WS_XT_SZ)             // float[32*1024]
#define WS_SQ      (WS_SUM + 131072ull)
#define WS_MU      (WS_SQ  + 131072ull)
#define WS_SIG     (WS_MU  + 131072ull)
#define WS_ACCUM   (WS_SIG + 131072ull)           // float[16] group |corr| sums
#define WS_LISTCNT (WS_ACCUM + 256ull)            // int
#define WS_LIST    (WS_LISTCNT + 256ull)          // int4[LIST_CAP]
#define WS_MASK    (WS_LIST + 1048576ull)         // uint[1024*1024] bit b = masked
#define WS_DIAG    (WS_MASK + 4194304ull)         // float[32*1024] diag corr values
// total ~141 MB

// ---------------- kernel 1: per-(b,w) stats + bf16 transpose ----------------
// grid (32 t-tiles, 16 w-tiles, 32 b), block 256
__global__ __launch_bounds__(256) void stats_transpose(
    const float* __restrict__ x, bf16_t* __restrict__ xT,
    float* __restrict__ sumb, float* __restrict__ sqb) {
  int b = blockIdx.z, t0 = blockIdx.x * 64, w0 = blockIdx.y * 64;
  __shared__ float tile[64][65];   // [w][t], padded
  __shared__ float red[2][256];
  int tid = threadIdx.x;
  int c = tid & 63, r0 = tid >> 6;
  float ps = 0.f, pq = 0.f;
  const float* xp = x + ((size_t)b * T_ + t0) * W_ + w0 + c;
#pragma unroll
  for (int r = r0; r < 64; r += 4) {
    float v = xp[(size_t)r * W_];
    ps += v; pq += v * v;
    tile[c][r] = v;               // transposed store, conflict-free (stride 65)
  }
  red[0][tid] = ps; red[1][tid] = pq;
  __syncthreads();
  if (tid < 64) {
    float s = red[0][tid] + red[0][tid + 64] + red[0][tid + 128] + red[0][tid + 192];
    float q = red[1][tid] + red[1][tid + 64] + red[1][tid + 128] + red[1][tid + 192];
    atomicAdd(&sumb[b * W_ + w0 + tid], s);
    atomicAdd(&sqb[b * W_ + w0 + tid], q);
  }
  int tl = tid & 63, wl0 = tid >> 6;
  bf16_t* xtp = xT + ((size_t)b * W_ + w0) * T_ + t0 + tl;
#pragma unroll
  for (int wl = wl0; wl < 64; wl += 4)
    xtp[(size_t)wl * T_] = (bf16_t)tile[wl][tl];   // coalesced bf16 write
}

__global__ void finalize_stats(const float* __restrict__ sumb,
                               const float* __restrict__ sqb,
                               float* __restrict__ mu, float* __restrict__ sig) {
  int idx = blockIdx.x * 256 + threadIdx.x;   // 32768 total
  float s = sumb[idx], q = sqb[idx];
  float m = s * (1.0f / 2048.0f);
  float var = (q - s * m) * (1.0f / 2047.0f);
  if (var < 0.f) var = 0.f;
  mu[idx] = m;
  sig[idx] = sqrtf(var);
}

// ---------------- kernel 2: batched Gram + corr epilogue (m97-style) ----------------
// grid (36 upper-tri 128x128 tiles, 32 b), block 256 = 4 waves, each wave a 64x64 quadrant
__global__ __launch_bounds__(256) void gram_kernel(
    const bf16_t* __restrict__ xT, const float* __restrict__ mu,
    const float* __restrict__ sig, unsigned int* __restrict__ mask,
    float* __restrict__ diagv, int* __restrict__ listcnt,
    int4* __restrict__ list, float* __restrict__ accum) {
  int b = blockIdx.y;
  // map blockIdx.x -> (ti, tj), tj >= ti, 8x8 tile grid
  int r = blockIdx.x, ti = 0;
  while (r >= 8 - ti) { r -= 8 - ti; ++ti; }
  int tj = ti + r;
  int i0 = ti * 128, j0 = tj * 128;

  const bf16_t* Ag = xT + ((size_t)b * W_ + i0) * T_;
  const bf16_t* Bg = xT + ((size_t)b * W_ + j0) * T_;

  __shared__ __attribute__((aligned(16))) bf16_t As[128 * 32];
  __shared__ __attribute__((aligned(16))) bf16_t Bs[128 * 32];

  int tid = threadIdx.x;
  int lane = tid & 63, wave = tid >> 6;
  int wm = wave >> 1, wn = wave & 1;

  f32x4 zero = {0.f, 0.f, 0.f, 0.f};
  f32x4 acc[4][4];
#pragma unroll
  for (int mi = 0; mi < 4; ++mi)
#pragma unroll
    for (int nj = 0; nj < 4; ++nj) acc[mi][nj] = zero;

  // LDS element offsets for MFMA fragments ([row][k] row-major, 32 k per row)
  int aoff = (wm * 64 + (lane & 15)) * 32 + (lane >> 4) * 8;
  int boff = (wn * 64 + (lane & 15)) * 32 + (lane >> 4) * 8;

  for (int k0 = 0; k0 < T_; k0 += 32) {
    __syncthreads();   // prior compute's ds_reads done before overwriting LDS
#pragma unroll
    for (int s = 0; s < 2; ++s) {
      int chunk = s * 256 + tid;            // 16B chunk id; 4 chunks per 64B row
      int row = chunk >> 2, kc = (chunk & 3) * 8;
      __builtin_amdgcn_global_load_lds(
          (const __attribute__((address_space(1))) void*)(Ag + (size_t)row * T_ + k0 + kc),
          (__attribute__((address_space(3))) void*)(As + chunk * 8), 16, 0, 0);
      __builtin_amdgcn_global_load_lds(
          (const __attribute__((address_space(1))) void*)(Bg + (size_t)row * T_ + k0 + kc),
          (__attribute__((address_space(3))) void*)(Bs + chunk * 8), 16, 0, 0);
    }
    __syncthreads();   // drains vmcnt -> LDS staged

    bf16x8 af[4], bfr[4];
#pragma unroll
    for (int mi = 0; mi < 4; ++mi) af[mi]  = *(const bf16x8*)(As + aoff + mi * 512);
#pragma unroll
    for (int nj = 0; nj < 4; ++nj) bfr[nj] = *(const bf16x8*)(Bs + boff + nj * 512);
#pragma unroll
    for (int mi = 0; mi < 4; ++mi)
#pragma unroll
      for (int nj = 0; nj < 4; ++nj)
        acc[mi][nj] = __builtin_amdgcn_mfma_f32_16x16x32_bf16(af[mi], bfr[nj], acc[mi][nj], 0, 0, 0);
  }

  // ---- epilogue: S -> corr -> {group |corr| accum, EMA mask/list} ----
  const float inv = 1.0f / 2047.0f;
  const float* mub = mu + b * W_;
  const float* sgb = sig + b * W_;
  bool diagquad = (ti == tj) && (wm == wn);
  float gsum = 0.f;

#pragma unroll
  for (int nj = 0; nj < 4; ++nj) {
    int j = j0 + wn * 64 + nj * 16 + (lane & 15);
    float muj = mub[j], sgj = sgb[j];
#pragma unroll
    for (int mi = 0; mi < 4; ++mi) {
#pragma unroll
      for (int rr = 0; rr < 4; ++rr) {
        int i = i0 + wm * 64 + mi * 16 + (lane >> 4) * 4 + rr;
        float cov = (acc[mi][nj][rr] - 2048.0f * mub[i] * muj) * inv;
        float corr = cov / (sgb[i] * sgj + 1e-8f);
        corr = fminf(1.0f, fmaxf(-1.0f, corr));
        if (diagquad && (i != j)) gsum += fabsf(corr);   // same 64-group by construction
        if (fabsf(corr) > 0.5f) {
          atomicOr(&mask[i * W_ + j], 1u << b);
          if (i == j) {
            diagv[b * W_ + i] = corr;
          } else {
            int p = atomicAdd(listcnt, 1);
            if (p < LIST_CAP) list[p] = make_int4(b, i, j, __float_as_int(corr));
          }
          if (ti != tj) {  // mirror into lower triangle
            atomicOr(&mask[j * W_ + i], 1u << b);
            int p = atomicAdd(listcnt, 1);
            if (p < LIST_CAP) list[p] = make_int4(b, j, i, __float_as_int(corr));
          }
        }
      }
    }
  }
  if (diagquad) {
    for (int o = 32; o > 0; o >>= 1) gsum += __shfl_down(gsum, o);
    if (lane == 0) atomicAdd(&accum[ti * 2 + wm], gsum);
  }
}

// ---------------- kernel 3: EMA scan apply ----------------
__global__ void ema_kernel(const float* __restrict__ ema,
                           const unsigned int* __restrict__ mask,
                           const float* __restrict__ diagv,
                           const int* __restrict__ listcnt,
                           const int4* __restrict__ list,
                           float* __restrict__ emaout) {
  int idx = blockIdx.x * 256 + threadIdx.x;   // 1M
  int i = idx >> 10, j = idx & 1023;
  float e = ema[idx];
  unsigned int m = mask[idx];
  if (m) {
    if (i == j) {
      for (int b = 0; b < 32; ++b)
        if ((m >> b) & 1u) e = 0.9f * e + 0.1f * diagv[b * W_ + i];
    } else {
      int cnt = *listcnt; if (cnt > LIST_CAP) cnt = LIST_CAP;
      for (int b = 0; b < 32; ++b) {
        if ((m >> b) & 1u) {
          for (int k = 0; k < cnt; ++k) {
            int4 t = list[k];
            if (t.x == b && t.y == i && t.z == j) {
              e = 0.9f * e + 0.1f * __int_as_float(t.w);
              break;
            }
          }
        }
      }
    }
  }
  emaout[idx] = e;
}

__global__ void corr_finalize(const float* __restrict__ accum, float* __restrict__ outc) {
  int g = threadIdx.x;
  if (g < 16) outc[g] = accum[g] * (1.0f / (32.0f * 4032.0f));
}

// ---------------- kernel 4: per-group expert MLP ----------------
// grid (32 t-tiles, 32 b, 4 gsets of 4 groups), block 256: gl=tid&3, tl=tid>>2
__global__ __launch_bounds__(256) void mlp_kernel(
    const float* __restrict__ x, const float* __restrict__ W1,
    const float* __restrict__ b1, const float* __restrict__ W2,
    const float* __restrict__ b2, float* __restrict__ out) {
  int b = blockIdx.y, t0 = blockIdx.x * 64, gs = blockIdx.z * 4;
  int tid = threadIdx.x;
  int gl = tid & 3, tl = tid >> 2;
  __shared__ float Wt[16 * 64 * 4];   // [(j*64+d)][gl] -> conflict-free lane reads
  __shared__ float b1s[16 * 4], W2s[16 * 4], b2s[4];
  for (int l = tid; l < 4096; l += 256) {
    int g2 = l & 3, jd = l >> 2;
    Wt[l] = W1[(size_t)(gs + g2) * 1024 + jd];
  }
  if (tid < 64) {
    int g2 = tid & 3, j = tid >> 2;
    b1s[j * 4 + g2] = b1[(gs + g2) * 16 + j];
    W2s[j * 4 + g2] = W2[(gs + g2) * 16 + j];
  }
  if (tid < 4) b2s[tid] = b2[gs + tid];
  __syncthreads();

  int g = gs + gl, t = t0 + tl;
  const float4* xp = (const float4*)(x + ((size_t)b * T_ + t) * W_ + g * D_);
  float h[16];
#pragma unroll
  for (int j = 0; j < 16; ++j) h[j] = b1s[j * 4 + gl];
#pragma unroll
  for (int d4 = 0; d4 < 16; ++d4) {
    float4 xv = xp[d4];
#pragma unroll
    for (int j = 0; j < 16; ++j) {
      const float* wp = &Wt[(j * 64 + d4 * 4) * 4 + gl];
      h[j] += xv.x * wp[0] + xv.y * wp[4] + xv.z * wp[8] + xv.w * wp[12];
    }
  }
  float o = b2s[gl];
#pragma unroll
  for (int j = 0; j < 16; ++j) o += fmaxf(h[j], 0.f) * W2s[j * 4 + gl];
  out[((size_t)b * T_ + t) * 16 + g] = o;
}

// ---------------- launch ----------------
extern "C" void kernel_launch(void* const* d_in, const int* in_sizes, int n_in,
                              void* d_out, int out_size, void* d_ws, size_t ws_size,
                              hipStream_t stream) {
  const float* x   = (const float*)d_in[0];
  const float* ema = (const float*)d_in[1];
  const float* W1  = (const float*)d_in[2];
  const float* b1  = (const float*)d_in[3];
  const float* W2  = (const float*)d_in[4];
  const float* b2  = (const float*)d_in[5];

  float* out    = (float*)d_out;          // [32][2048][16]
  float* outc   = out + 1048576;          // [16]
  float* outema = outc + 16;              // [1024][1024]

  char* ws = (char*)d_ws;                 // needs ~141 MB
  bf16_t* xT        = (bf16_t*)(ws + WS_XT);
  float* sumb       = (float*)(ws + WS_SUM);
  float* sqb        = (float*)(ws + WS_SQ);
  float* mub        = (float*)(ws + WS_MU);
  float* sigb       = (float*)(ws + WS_SIG);
  float* accum      = (float*)(ws + WS_ACCUM);
  int*   listcnt    = (int*)(ws + WS_LISTCNT);
  int4*  list       = (int4*)(ws + WS_LIST);
  unsigned int* msk = (unsigned int*)(ws + WS_MASK);
  float* diagv      = (float*)(ws + WS_DIAG);

  hipMemsetAsync(ws + WS_SUM, 0, 262144, stream);       // sum + sq
  hipMemsetAsync(ws + WS_ACCUM, 0, 512, stream);        // accum + listcnt
  hipMemsetAsync(ws + WS_MASK, 0, 4194304, stream);     // mask bitmap

  stats_transpose<<<dim3(32, 16, 32), 256, 0, stream>>>(x, xT, sumb, sqb);
  finalize_stats<<<128, 256, 0, stream>>>(sumb, sqb, mub, sigb);
  gram_kernel<<<dim3(36, 32), 256, 0, stream>>>(xT, mub, sigb, msk, diagv, listcnt, list, accum);
  ema_kernel<<<4096, 256, 0, stream>>>(ema, msk, diagv, listcnt, list, outema);
  corr_finalize<<<1, 16, 0, stream>>>(accum, outc);
  mlp_kernel<<<dim3(32, 32, 4), 256, 0, stream>>>(x, W1, b1, W2, b2, out);
}

// Round 2
// 727.998 us; speedup vs baseline: 1.0470x; 1.0470x over previous
//
#include <hip/hip_runtime.h>
#include <hip/hip_bf16.h>
#include <stdint.h>

// Problem constants
#define B_   32
#define T_   2048
#define W_   1024
#define G_   16
#define D_   64
#define LIST_CAP 65536
#define BK   64

typedef __bf16 bf16_t;
typedef __bf16 bf16x8 __attribute__((ext_vector_type(8)));
typedef float  f32x4  __attribute__((ext_vector_type(4)));

// ---------------- workspace layout (bytes) ----------------
#define WS_XT      0ull
#define WS_XT_SZ   (134217728ull)                 // 32*1024*2048*2
#define WS_SUM     (WS_XT + WS_XT_SZ)             // float[32*1024]
#define WS_SQ      (WS_SUM + 131072ull)
#define WS_MU      (WS_SQ  + 131072ull)
#define WS_SIG     (WS_MU  + 131072ull)
#define WS_ACCUM   (WS_SIG + 131072ull)           // float[16] group |corr| sums
#define WS_LISTCNT (WS_ACCUM + 256ull)            // int
#define WS_LIST    (WS_LISTCNT + 256ull)          // int4[LIST_CAP]
#define WS_MASK    (WS_LIST + 1048576ull)         // uint[1024*1024] bit b = masked
#define WS_DIAG    (WS_MASK + 4194304ull)         // float[32*1024]

// ---------------- kernel 1: per-(b,w) stats + bf16 transpose ----------------
// grid (32 t-tiles, 16 w-tiles, 32 b), block 256. float4 in, bf16x8 out.
__global__ __launch_bounds__(256) void stats_transpose(
    const float* __restrict__ x, bf16_t* __restrict__ xT,
    float* __restrict__ sumb, float* __restrict__ sqb) {
  int b = blockIdx.z, t0 = blockIdx.x * 64, w0 = blockIdx.y * 64;
  __shared__ float tile[64][65];        // [w][t], padded
  __shared__ float rs[64][17], rq[64][17];
  int tid = threadIdx.x;
  int wc = tid & 15, tr = tid >> 4;     // wc: float4 col (4 w's), tr: t row 0..15
  float4 s4 = {0.f, 0.f, 0.f, 0.f}, q4 = {0.f, 0.f, 0.f, 0.f};
  const float4* xp = (const float4*)(x + ((size_t)b * T_ + t0) * W_ + w0);
#pragma unroll
  for (int p = 0; p < 4; ++p) {
    int t = tr + 16 * p;
    float4 v = xp[(size_t)t * 256 + wc];   // 256 = W_/4 row stride in float4
    s4.x += v.x; s4.y += v.y; s4.z += v.z; s4.w += v.w;
    q4.x += v.x * v.x; q4.y += v.y * v.y; q4.z += v.z * v.z; q4.w += v.w * v.w;
    tile[4 * wc + 0][t] = v.x;
    tile[4 * wc + 1][t] = v.y;
    tile[4 * wc + 2][t] = v.z;
    tile[4 * wc + 3][t] = v.w;
  }
  rs[4 * wc + 0][tr] = s4.x; rs[4 * wc + 1][tr] = s4.y;
  rs[4 * wc + 2][tr] = s4.z; rs[4 * wc + 3][tr] = s4.w;
  rq[4 * wc + 0][tr] = q4.x; rq[4 * wc + 1][tr] = q4.y;
  rq[4 * wc + 2][tr] = q4.z; rq[4 * wc + 3][tr] = q4.w;
  __syncthreads();
  if (tid < 64) {
    float s = 0.f, q = 0.f;
#pragma unroll
    for (int i = 0; i < 16; ++i) { s += rs[tid][i]; q += rq[tid][i]; }
    atomicAdd(&sumb[b * W_ + w0 + tid], s);
    atomicAdd(&sqb[b * W_ + w0 + tid], q);
  }
  // write phase: 64 w-rows x 8 chunks of 8 bf16 (16B stores)
  int c = tid & 7, wv = tid >> 3;       // c: chunk in row, wv: w row (2 passes)
#pragma unroll
  for (int p = 0; p < 2; ++p) {
    int w = wv + 32 * p;
    const float* src = &tile[w][c * 8];
    bf16x8 o;
#pragma unroll
    for (int k = 0; k < 8; ++k) o[k] = (bf16_t)src[k];
    *(bf16x8*)(xT + ((size_t)b * W_ + w0 + w) * T_ + t0 + c * 8) = o;
  }
}

__global__ void finalize_stats(const float* __restrict__ sumb,
                               const float* __restrict__ sqb,
                               float* __restrict__ mu, float* __restrict__ sig) {
  int idx = blockIdx.x * 256 + threadIdx.x;   // 32768 total
  float s = sumb[idx], q = sqb[idx];
  float m = s * (1.0f / 2048.0f);
  float var = (q - s * m) * (1.0f / 2047.0f);
  if (var < 0.f) var = 0.f;
  mu[idx] = m;
  sig[idx] = sqrtf(var);
}

// ---------------- kernel 2: batched Gram + corr epilogue ----------------
// 1-D grid 1152 = 8 xcd * 4 sub-batches * 36 upper-tri tiles; block 256 = 4 waves.
// XCD-pinned: batch b = sub*8 + (id&7) so each 4MB xT slice stays in one L2.
// BK=64 staged with chunk-XOR swizzle (LDS row = 128B, slot^(row&7)) -> 2-way reads.
__global__ __launch_bounds__(256) void gram_kernel(
    const bf16_t* __restrict__ xT, const float* __restrict__ mu,
    const float* __restrict__ sig, unsigned int* __restrict__ mask,
    float* __restrict__ diagv, int* __restrict__ listcnt,
    int4* __restrict__ list, float* __restrict__ accum) {
  int id = blockIdx.x;
  int xcd = id & 7;
  int idx = id >> 3;            // 0..143
  int sub = idx / 36;           // 0..3
  int rt  = idx % 36;
  int b = sub * 8 + xcd;
  int r = rt, ti = 0;
  while (r >= 8 - ti) { r -= 8 - ti; ++ti; }
  int tj = ti + r;
  int i0 = ti * 128, j0 = tj * 128;

  const bf16_t* Ag = xT + ((size_t)b * W_ + i0) * T_;
  const bf16_t* Bg = xT + ((size_t)b * W_ + j0) * T_;

  __shared__ __attribute__((aligned(16))) bf16_t As[128 * BK];  // 16 KB
  __shared__ __attribute__((aligned(16))) bf16_t Bs[128 * BK];  // 16 KB

  int tid = threadIdx.x;
  int lane = tid & 63, wave = tid >> 6;
  int wm = wave >> 1, wn = wave & 1;

  f32x4 zero = {0.f, 0.f, 0.f, 0.f};
  f32x4 acc[4][4];
#pragma unroll
  for (int mi = 0; mi < 4; ++mi)
#pragma unroll
    for (int nj = 0; nj < 4; ++nj) acc[mi][nj] = zero;

  // fragment base rows
  int arow = wm * 64 + (lane & 15);
  int brow = wn * 64 + (lane & 15);
  int q = lane >> 4;                       // k-quarter within 32-slice

  for (int k0 = 0; k0 < T_; k0 += BK) {
    __syncthreads();   // prior ds_reads done before overwriting LDS
    // stage 128 rows x 64 k each matrix: 1024 chunks of 16B, 4 per thread
#pragma unroll
    for (int s = 0; s < 4; ++s) {
      int c = s * 256 + tid;               // linear LDS chunk
      int row = c >> 3, slot = c & 7;
      int gslot = slot ^ (row & 7);        // XOR swizzle (global source permute)
      __builtin_amdgcn_global_load_lds(
          (const __attribute__((address_space(1))) void*)(Ag + (size_t)row * T_ + k0 + gslot * 8),
          (__attribute__((address_space(3))) void*)(As + c * 8), 16, 0, 0);
      __builtin_amdgcn_global_load_lds(
          (const __attribute__((address_space(1))) void*)(Bg + (size_t)row * T_ + k0 + gslot * 8),
          (__attribute__((address_space(3))) void*)(Bs + c * 8), 16, 0, 0);
    }
    __syncthreads();   // drains vmcnt -> LDS staged

#pragma unroll
    for (int s2 = 0; s2 < 2; ++s2) {       // two 32-k MFMA steps per stage
      bf16x8 af[4], bfr[4];
#pragma unroll
      for (int mi = 0; mi < 4; ++mi) {
        int row = arow + mi * 16;
        af[mi] = *(const bf16x8*)(As + row * BK + ((s2 * 4 + q) ^ (row & 7)) * 8);
      }
#pragma unroll
      for (int nj = 0; nj < 4; ++nj) {
        int row = brow + nj * 16;
        bfr[nj] = *(const bf16x8*)(Bs + row * BK + ((s2 * 4 + q) ^ (row & 7)) * 8);
      }
#pragma unroll
      for (int mi = 0; mi < 4; ++mi)
#pragma unroll
        for (int nj = 0; nj < 4; ++nj)
          acc[mi][nj] = __builtin_amdgcn_mfma_f32_16x16x32_bf16(af[mi], bfr[nj], acc[mi][nj], 0, 0, 0);
    }
  }

  // ---- epilogue: S -> corr -> {group |corr| accum, EMA mask/list} ----
  const float inv = 1.0f / 2047.0f;
  const float* mub = mu + b * W_;
  const float* sgb = sig + b * W_;
  bool diagquad = (ti == tj) && (wm == wn);
  float gsum = 0.f;

#pragma unroll
  for (int nj = 0; nj < 4; ++nj) {
    int j = j0 + wn * 64 + nj * 16 + (lane & 15);
    float muj = mub[j], sgj = sgb[j];
#pragma unroll
    for (int mi = 0; mi < 4; ++mi) {
#pragma unroll
      for (int rr = 0; rr < 4; ++rr) {
        int i = i0 + wm * 64 + mi * 16 + (lane >> 4) * 4 + rr;
        float cov = (acc[mi][nj][rr] - 2048.0f * mub[i] * muj) * inv;
        float corr = cov / (sgb[i] * sgj + 1e-8f);
        corr = fminf(1.0f, fmaxf(-1.0f, corr));
        if (diagquad && (i != j)) gsum += fabsf(corr);
        if (fabsf(corr) > 0.5f) {
          atomicOr(&mask[i * W_ + j], 1u << b);
          if (i == j) {
            diagv[b * W_ + i] = corr;
          } else {
            int p = atomicAdd(listcnt, 1);
            if (p < LIST_CAP) list[p] = make_int4(b, i, j, __float_as_int(corr));
          }
          if (ti != tj) {
            atomicOr(&mask[j * W_ + i], 1u << b);
            int p = atomicAdd(listcnt, 1);
            if (p < LIST_CAP) list[p] = make_int4(b, j, i, __float_as_int(corr));
          }
        }
      }
    }
  }
  if (diagquad) {
    for (int o = 32; o > 0; o >>= 1) gsum += __shfl_down(gsum, o);
    if (lane == 0) atomicAdd(&accum[ti * 2 + wm], gsum);
  }
}

// ---------------- kernel 3: EMA scan apply ----------------
__global__ void ema_kernel(const float* __restrict__ ema,
                           const unsigned int* __restrict__ mask,
                           const float* __restrict__ diagv,
                           const int* __restrict__ listcnt,
                           const int4* __restrict__ list,
                           float* __restrict__ emaout) {
  int idx = blockIdx.x * 256 + threadIdx.x;   // 1M
  int i = idx >> 10, j = idx & 1023;
  float e = ema[idx];
  unsigned int m = mask[idx];
  if (m) {
    if (i == j) {
      for (int b = 0; b < 32; ++b)
        if ((m >> b) & 1u) e = 0.9f * e + 0.1f * diagv[b * W_ + i];
    } else {
      int cnt = *listcnt; if (cnt > LIST_CAP) cnt = LIST_CAP;
      for (int b = 0; b < 32; ++b) {
        if ((m >> b) & 1u) {
          for (int k = 0; k < cnt; ++k) {
            int4 t = list[k];
            if (t.x == b && t.y == i && t.z == j) {
              e = 0.9f * e + 0.1f * __int_as_float(t.w);
              break;
            }
          }
        }
      }
    }
  }
  emaout[idx] = e;
}

__global__ void corr_finalize(const float* __restrict__ accum, float* __restrict__ outc) {
  int g = threadIdx.x;
  if (g < 16) outc[g] = accum[g] * (1.0f / (32.0f * 4032.0f));
}

// ---------------- kernel 4: per-group expert MLP ----------------
__global__ __launch_bounds__(256) void mlp_kernel(
    const float* __restrict__ x, const float* __restrict__ W1,
    const float* __restrict__ b1, const float* __restrict__ W2,
    const float* __restrict__ b2, float* __restrict__ out) {
  int b = blockIdx.y, t0 = blockIdx.x * 64, gs = blockIdx.z * 4;
  int tid = threadIdx.x;
  int gl = tid & 3, tl = tid >> 2;
  __shared__ float Wt[16 * 64 * 4];
  __shared__ float b1s[16 * 4], W2s[16 * 4], b2s[4];
  for (int l = tid; l < 4096; l += 256) {
    int g2 = l & 3, jd = l >> 2;
    Wt[l] = W1[(size_t)(gs + g2) * 1024 + jd];
  }
  if (tid < 64) {
    int g2 = tid & 3, j = tid >> 2;
    b1s[j * 4 + g2] = b1[(gs + g2) * 16 + j];
    W2s[j * 4 + g2] = W2[(gs + g2) * 16 + j];
  }
  if (tid < 4) b2s[tid] = b2[gs + tid];
  __syncthreads();

  int g = gs + gl, t = t0 + tl;
  const float4* xp = (const float4*)(x + ((size_t)b * T_ + t) * W_ + g * D_);
  float h[16];
#pragma unroll
  for (int j = 0; j < 16; ++j) h[j] = b1s[j * 4 + gl];
#pragma unroll
  for (int d4 = 0; d4 < 16; ++d4) {
    float4 xv = xp[d4];
#pragma unroll
    for (int j = 0; j < 16; ++j) {
      const float* wp = &Wt[(j * 64 + d4 * 4) * 4 + gl];
      h[j] += xv.x * wp[0] + xv.y * wp[4] + xv.z * wp[8] + xv.w * wp[12];
    }
  }
  float o = b2s[gl];
#pragma unroll
  for (int j = 0; j < 16; ++j) o += fmaxf(h[j], 0.f) * W2s[j * 4 + gl];
  out[((size_t)b * T_ + t) * 16 + g] = o;
}

// ---------------- launch ----------------
extern "C" void kernel_launch(void* const* d_in, const int* in_sizes, int n_in,
                              void* d_out, int out_size, void* d_ws, size_t ws_size,
                              hipStream_t stream) {
  const float* x   = (const float*)d_in[0];
  const float* ema = (const float*)d_in[1];
  const float* W1  = (const float*)d_in[2];
  const float* b1  = (const float*)d_in[3];
  const float* W2  = (const float*)d_in[4];
  const float* b2  = (const float*)d_in[5];

  float* out    = (float*)d_out;          // [32][2048][16]
  float* outc   = out + 1048576;          // [16]
  float* outema = outc + 16;              // [1024][1024]

  char* ws = (char*)d_ws;
  bf16_t* xT        = (bf16_t*)(ws + WS_XT);
  float* sumb       = (float*)(ws + WS_SUM);
  float* sqb        = (float*)(ws + WS_SQ);
  float* mub        = (float*)(ws + WS_MU);
  float* sigb       = (float*)(ws + WS_SIG);
  float* accum      = (float*)(ws + WS_ACCUM);
  int*   listcnt    = (int*)(ws + WS_LISTCNT);
  int4*  list       = (int4*)(ws + WS_LIST);
  unsigned int* msk = (unsigned int*)(ws + WS_MASK);
  float* diagv      = (float*)(ws + WS_DIAG);

  hipMemsetAsync(ws + WS_SUM, 0, 262144, stream);       // sum + sq
  hipMemsetAsync(ws + WS_ACCUM, 0, 512, stream);        // accum + listcnt
  hipMemsetAsync(ws + WS_MASK, 0, 4194304, stream);     // mask bitmap

  stats_transpose<<<dim3(32, 16, 32), 256, 0, stream>>>(x, xT, sumb, sqb);
  finalize_stats<<<128, 256, 0, stream>>>(sumb, sqb, mub, sigb);
  gram_kernel<<<1152, 256, 0, stream>>>(xT, mub, sigb, msk, diagv, listcnt, list, accum);
  ema_kernel<<<4096, 256, 0, stream>>>(ema, msk, diagv, listcnt, list, outema);
  corr_finalize<<<1, 16, 0, stream>>>(accum, outc);
  mlp_kernel<<<dim3(32, 32, 4), 256, 0, stream>>>(x, W1, b1, W2, b2, out);
}